// Round 4
// baseline (935.359 us; speedup 1.0000x reference)
//
#include <hip/hip_runtime.h>
#include <hip/hip_bf16.h>
#include <math.h>

// Problem constants (B=4, S=2048, Hd=1024, h=16, d=64). fp32 in/out per the
// reference; bf16 internally (MFMA) with fp32 accumulation.
#define B_SZ   4
#define S_LEN  2048
#define HD     1024
#define NHEAD  16
#define DHEAD  64
#define N3     3072          // 3*Hd
#define M_ROWS 8192          // B*S

typedef __bf16 bf16_t;
typedef __bf16 bf16x4 __attribute__((ext_vector_type(4)));
typedef __bf16 bf16x8 __attribute__((ext_vector_type(8)));
typedef float  floatx4 __attribute__((ext_vector_type(4)));

__device__ __forceinline__ float bf2f(bf16_t x) { return (float)x; }
__device__ __forceinline__ bf16_t f2bf(float f) { return (bf16_t)f; }  // RNE fptrunc

__device__ __forceinline__ bf16x8 cvt8(const float4 lo, const float4 hi) {
    bf16x8 r;
    r[0] = (bf16_t)lo.x; r[1] = (bf16_t)lo.y; r[2] = (bf16_t)lo.z; r[3] = (bf16_t)lo.w;
    r[4] = (bf16_t)hi.x; r[5] = (bf16_t)hi.y; r[6] = (bf16_t)hi.z; r[7] = (bf16_t)hi.w;
    return r;
}

// ---------------------------------------------------------------------------
// Kernel 1: qkv = X @ W^T + b (fp32 in, bf16 MFMA, fp32 acc), fused RoPE on
// q,k. q,k scattered to [b][h][s][d]; v scattered TRANSPOSED to [b][h][d][s]
// so the attention kernel can stage V^T with coalesced loads (kills the
// round-3 4-way-conflict LDS transpose scatter).
// ---------------------------------------------------------------------------
__global__ __launch_bounds__(256, 3)
void qkv_rope_kernel(const float* __restrict__ X, const float* __restrict__ W,
                     const float* __restrict__ bias,
                     bf16_t* __restrict__ qws, bf16_t* __restrict__ kws,
                     bf16_t* __restrict__ vws)
{
    __shared__ bf16_t As[128 * 32];   // 8 KB, [row][32] bf16 (16-dword rows)
    __shared__ bf16_t Bs[128 * 32];   // 8 KB

    const int tid  = threadIdx.x;
    const int wave = tid >> 6;
    const int lane = tid & 63;
    const int l15  = lane & 15;
    const int quad = lane >> 4;
    const int wm   = wave >> 1;
    const int wn   = wave & 1;
    const int m0   = blockIdx.y * 128;
    const int n0   = blockIdx.x * 128;

    const int b0   = tid;
    const int b1   = tid + 256;
    const int r0   = b0 >> 2, c0 = (b0 & 3) * 8;
    const int r1   = b1 >> 2, c1 = (b1 & 3) * 8;

    const float* gA0 = X + (size_t)(m0 + r0) * HD + c0;
    const float* gA1 = X + (size_t)(m0 + r1) * HD + c1;
    const float* gB0 = W + (size_t)(n0 + r0) * HD + c0;
    const float* gB1 = W + (size_t)(n0 + r1) * HD + c1;

    floatx4 acc[4][4];
#pragma unroll
    for (int i = 0; i < 4; ++i)
#pragma unroll
        for (int j = 0; j < 4; ++j)
            acc[i][j] = (floatx4){0.f, 0.f, 0.f, 0.f};

    float4 a0l = *(const float4*)(gA0);     float4 a0h = *(const float4*)(gA0 + 4);
    float4 a1l = *(const float4*)(gA1);     float4 a1h = *(const float4*)(gA1 + 4);
    float4 w0l = *(const float4*)(gB0);     float4 w0h = *(const float4*)(gB0 + 4);
    float4 w1l = *(const float4*)(gB1);     float4 w1h = *(const float4*)(gB1 + 4);

    for (int kt = 0; kt < 32; ++kt) {
        *(bf16x8*)(As + r0 * 32 + c0) = cvt8(a0l, a0h);
        *(bf16x8*)(As + r1 * 32 + c1) = cvt8(a1l, a1h);
        *(bf16x8*)(Bs + r0 * 32 + c0) = cvt8(w0l, w0h);
        *(bf16x8*)(Bs + r1 * 32 + c1) = cvt8(w1l, w1h);
        __syncthreads();

        if (kt + 1 < 32) {
            const int k0 = (kt + 1) * 32;
            a0l = *(const float4*)(gA0 + k0);  a0h = *(const float4*)(gA0 + k0 + 4);
            a1l = *(const float4*)(gA1 + k0);  a1h = *(const float4*)(gA1 + k0 + 4);
            w0l = *(const float4*)(gB0 + k0);  w0h = *(const float4*)(gB0 + k0 + 4);
            w1l = *(const float4*)(gB1 + k0);  w1h = *(const float4*)(gB1 + k0 + 4);
        }

        bf16x8 af[4], bfr[4];
#pragma unroll
        for (int t = 0; t < 4; ++t) {
            af[t]  = *(const bf16x8*)(As + (wm * 64 + t * 16 + l15) * 32 + quad * 8);
            bfr[t] = *(const bf16x8*)(Bs + (wn * 64 + t * 16 + l15) * 32 + quad * 8);
        }
#pragma unroll
        for (int i = 0; i < 4; ++i)
#pragma unroll
            for (int j = 0; j < 4; ++j)
                acc[i][j] = __builtin_amdgcn_mfma_f32_16x16x32_bf16(
                    af[i], bfr[j], acc[i][j], 0, 0, 0);
        __syncthreads();
    }

    // Epilogue: bias + RoPE + scatter. C/D: col=lane&15, row=quad*4+reg.
#pragma unroll
    for (int i = 0; i < 4; ++i) {
        const int mrow_base = m0 + wm * 64 + i * 16 + quad * 4;
#pragma unroll
        for (int j = 0; j < 2; ++j) {
            const int n1 = n0 + wn * 64 + j * 16 + l15;    // dim in [0,32)
            const int n2 = n1 + 32;
            const float b1 = bias[n1];
            const float b2 = bias[n2];
            const int which = n1 >> 10;          // 0=q 1=k 2=v  (wave-uniform)
            const int hd    = n1 & 1023;
            const int head  = hd >> 6;
            const int dim   = hd & 63;           // < 32 by construction
            const float inv_freq = expf(-(float)dim * 0.28782313662425572f);
#pragma unroll
            for (int r = 0; r < 4; ++r) {
                const int mrow = mrow_base + r;
                const int s    = mrow & (S_LEN - 1);
                const int bb   = mrow >> 11;
                float x1 = acc[i][j][r]     + b1;
                float x2 = acc[i][j + 2][r] + b2;
                if (which < 2) {
                    const float ang = (float)s * inv_freq;
                    const float cs = cosf(ang);
                    const float sn = sinf(ang);
                    const float o1 = x1 * cs - x2 * sn;
                    const float o2 = x2 * cs + x1 * sn;
                    bf16_t* outp = (which == 0) ? qws : kws;
                    const size_t off = ((size_t)(bb * NHEAD + head) * S_LEN + s) * DHEAD + dim;
                    outp[off]      = f2bf(o1);
                    outp[off + 32] = f2bf(o2);
                } else {
                    // v: transposed layout [b][h][d][s]
                    const size_t off = ((size_t)(bb * NHEAD + head) * DHEAD + dim) * S_LEN + s;
                    vws[off]                = f2bf(x1);
                    vws[off + 32 * S_LEN]   = f2bf(x2);
                }
            }
        }
    }
}

// ---------------------------------------------------------------------------
// Kernel 2: flash attention. Block = (bh, 128 q-rows); 4 waves x 32 q-rows.
// Q fragments persist in registers (loaded once). K [t][d] and V^T [d][t]
// staged coalesced into LDS (stride 72). P round-trips a wave-private LDS
// slab with stride 76 -> conflict-free scalar writes (quads spread
// {0,24,16,8} over banks), b64 reads. Register prefetch of next K/V tile.
// ---------------------------------------------------------------------------
#define STK 72
#define STP 76

__global__ __launch_bounds__(256, 3)
void attn_kernel(const bf16_t* __restrict__ qws, const bf16_t* __restrict__ kws,
                 const bf16_t* __restrict__ vws, float* __restrict__ out)
{
    __shared__ bf16_t Ks[64 * STK];    // 9216 B
    __shared__ bf16_t Vs[64 * STK];    // 9216 B  (V^T: [d][t])
    __shared__ bf16_t Ps[128 * STP];   // 19456 B (wave-private 32-row slabs)

    const int tid  = threadIdx.x;
    const int wave = tid >> 6;
    const int lane = tid & 63;
    const int l15  = lane & 15;
    const int quad = lane >> 4;
    const int qt   = blockIdx.x;          // 0..15 (128 q-rows each)
    const int bh   = blockIdx.y;          // 0..63
    const size_t baseS = (size_t)bh * S_LEN * DHEAD;   // q,k: [s][d]
    const size_t baseV = (size_t)bh * DHEAD * S_LEN;   // v:   [d][s]
    const int q0 = qt * 128 + wave * 32;

    // Q fragments: persist across the whole loop. A[m=q][k=d].
    bf16x8 aq[2][2];
#pragma unroll
    for (int qsub = 0; qsub < 2; ++qsub)
#pragma unroll
        for (int kb = 0; kb < 2; ++kb)
            aq[qsub][kb] = *(const bf16x8*)(qws + baseS +
                (size_t)(q0 + qsub * 16 + l15) * DHEAD + kb * 32 + quad * 8);

    // staging coords: 64 rows x 64 cols, 2 x uint4 per thread per matrix
    const int srow = tid >> 2;
    const int scol = (tid & 3) * 8;

    uint4 kreg[2], vreg[2];
#pragma unroll
    for (int jj = 0; jj < 2; ++jj) {
        kreg[jj] = *(const uint4*)(kws + baseS + (size_t)srow * DHEAD + scol + jj * 32);
        vreg[jj] = *(const uint4*)(vws + baseV + (size_t)srow * S_LEN + scol + jj * 32);
    }

    float m_i[2][4], l_i[2][4], alpha[2][4];
    floatx4 o_acc[2][4];
#pragma unroll
    for (int qsub = 0; qsub < 2; ++qsub) {
#pragma unroll
        for (int r = 0; r < 4; ++r) { m_i[qsub][r] = -1e30f; l_i[qsub][r] = 0.0f; }
#pragma unroll
        for (int dt = 0; dt < 4; ++dt) o_acc[qsub][dt] = (floatx4){0.f, 0.f, 0.f, 0.f};
    }

    for (int kt = 0; kt < 32; ++kt) {
        // write prefetched tile to LDS
#pragma unroll
        for (int jj = 0; jj < 2; ++jj) {
            *(uint4*)(Ks + srow * STK + scol + jj * 32) = kreg[jj];
            *(uint4*)(Vs + srow * STK + scol + jj * 32) = vreg[jj];
        }
        __syncthreads();

        // prefetch next tile
        if (kt + 1 < 32) {
            const int t0 = (kt + 1) * 64;
#pragma unroll
            for (int jj = 0; jj < 2; ++jj) {
                kreg[jj] = *(const uint4*)(kws + baseS + (size_t)(t0 + srow) * DHEAD + scol + jj * 32);
                vreg[jj] = *(const uint4*)(vws + baseV + (size_t)srow * S_LEN + t0 + scol + jj * 32);
            }
        }

        // K fragments: B[n=t][k=d]
        bf16x8 bk[2][4];
#pragma unroll
        for (int kb = 0; kb < 2; ++kb)
#pragma unroll
            for (int nt = 0; nt < 4; ++nt)
                bk[kb][nt] = *(const bf16x8*)(Ks + (nt * 16 + l15) * STK + kb * 32 + quad * 8);

        // scores
        floatx4 sc[2][4];
#pragma unroll
        for (int qsub = 0; qsub < 2; ++qsub)
#pragma unroll
            for (int nt = 0; nt < 4; ++nt) {
                floatx4 s4 = (floatx4){0.f, 0.f, 0.f, 0.f};
#pragma unroll
                for (int kb = 0; kb < 2; ++kb)
                    s4 = __builtin_amdgcn_mfma_f32_16x16x32_bf16(
                        aq[qsub][kb], bk[kb][nt], s4, 0, 0, 0);
                sc[qsub][nt] = s4 * 0.125f;
            }

        // online softmax + P store (wave-private Ps slab, no barrier needed)
#pragma unroll
        for (int qsub = 0; qsub < 2; ++qsub) {
            float mnew[4], rsum[4];
#pragma unroll
            for (int r = 0; r < 4; ++r) {
                float mx = fmaxf(fmaxf(sc[qsub][0][r], sc[qsub][1][r]),
                                 fmaxf(sc[qsub][2][r], sc[qsub][3][r]));
#pragma unroll
                for (int off = 1; off < 16; off <<= 1)
                    mx = fmaxf(mx, __shfl_xor(mx, off, 64));
                mnew[r]        = fmaxf(m_i[qsub][r], mx);
                alpha[qsub][r] = __expf(m_i[qsub][r] - mnew[r]);
                rsum[r]        = 0.0f;
            }
#pragma unroll
            for (int nt = 0; nt < 4; ++nt)
#pragma unroll
                for (int r = 0; r < 4; ++r) {
                    const float p = __expf(sc[qsub][nt][r] - mnew[r]);
                    const bf16_t pb = f2bf(p);
                    rsum[r] += bf2f(pb);
                    Ps[(wave * 32 + qsub * 16 + quad * 4 + r) * STP + nt * 16 + l15] = pb;
                }
#pragma unroll
            for (int r = 0; r < 4; ++r) {
                float sm = rsum[r];
#pragma unroll
                for (int off = 1; off < 16; off <<= 1)
                    sm += __shfl_xor(sm, off, 64);
                l_i[qsub][r] = l_i[qsub][r] * alpha[qsub][r] + sm;
                m_i[qsub][r] = mnew[r];
            }
        }

        // rescale O
#pragma unroll
        for (int qsub = 0; qsub < 2; ++qsub)
#pragma unroll
            for (int dt = 0; dt < 4; ++dt)
#pragma unroll
                for (int r = 0; r < 4; ++r)
                    o_acc[qsub][dt][r] *= alpha[qsub][r];

        // O += P V : A = P (LDS), B = V^T (LDS, [d][t])
#pragma unroll
        for (int kb = 0; kb < 2; ++kb) {
            bf16x8 bv[4];
#pragma unroll
            for (int dt = 0; dt < 4; ++dt)
                bv[dt] = *(const bf16x8*)(Vs + (dt * 16 + l15) * STK + kb * 32 + quad * 8);
#pragma unroll
            for (int qsub = 0; qsub < 2; ++qsub) {
                const int pbase = (wave * 32 + qsub * 16 + l15) * STP + kb * 32 + quad * 8;
                bf16x4 plo = *(const bf16x4*)(Ps + pbase);
                bf16x4 phi = *(const bf16x4*)(Ps + pbase + 4);
                bf16x8 ap = __builtin_shufflevector(plo, phi, 0, 1, 2, 3, 4, 5, 6, 7);
#pragma unroll
                for (int dt = 0; dt < 4; ++dt)
                    o_acc[qsub][dt] = __builtin_amdgcn_mfma_f32_16x16x32_bf16(
                        ap, bv[dt], o_acc[qsub][dt], 0, 0, 0);
            }
        }
        __syncthreads();
    }

    // normalize + store out[b][s][h*64+d] (fp32)
    const int bb = bh >> 4, hh = bh & 15;
#pragma unroll
    for (int qsub = 0; qsub < 2; ++qsub)
#pragma unroll
        for (int r = 0; r < 4; ++r) {
            const float inv = 1.0f / l_i[qsub][r];
            const int s = q0 + qsub * 16 + quad * 4 + r;
            const size_t off0 = ((size_t)(bb * S_LEN + s)) * HD + hh * DHEAD;
#pragma unroll
            for (int dt = 0; dt < 4; ++dt)
                out[off0 + dt * 16 + l15] = o_acc[qsub][dt][r] * inv;
        }
}

extern "C" void kernel_launch(void* const* d_in, const int* in_sizes, int n_in,
                              void* d_out, int out_size, void* d_ws, size_t ws_size,
                              hipStream_t stream) {
    const float* X    = (const float*)d_in[0];   // (4,2048,1024) fp32
    const float* W    = (const float*)d_in[1];   // (3072,1024) fp32
    const float* bias = (const float*)d_in[2];   // (3072,) fp32
    float* out = (float*)d_out;                  // (4,2048,1024) fp32

    const size_t per = (size_t)B_SZ * NHEAD * S_LEN * DHEAD;   // 8.39M elems
    bf16_t* qws = (bf16_t*)d_ws;
    bf16_t* kws = qws + per;
    bf16_t* vws = kws + per;

    qkv_rope_kernel<<<dim3(N3 / 128, M_ROWS / 128), 256, 0, stream>>>(
        X, W, bias, qws, kws, vws);
    attn_kernel<<<dim3(S_LEN / 128, B_SZ * NHEAD), 256, 0, stream>>>(
        qws, kws, vws, out);
}

// Round 5
// 417.398 us; speedup vs baseline: 2.2409x; 2.2409x over previous
//
#include <hip/hip_runtime.h>
#include <hip/hip_bf16.h>
#include <math.h>

// Problem constants (B=4, S=2048, Hd=1024, h=16, d=64). fp32 in/out per the
// reference; bf16 internally (MFMA) with fp32 accumulation.
#define B_SZ   4
#define S_LEN  2048
#define HD     1024
#define NHEAD  16
#define DHEAD  64
#define N3     3072          // 3*Hd
#define M_ROWS 8192          // B*S

typedef __bf16 bf16_t;
typedef __bf16 bf16x4 __attribute__((ext_vector_type(4)));
typedef __bf16 bf16x8 __attribute__((ext_vector_type(8)));
typedef float  floatx4 __attribute__((ext_vector_type(4)));

__device__ __forceinline__ float bf2f(bf16_t x) { return (float)x; }
__device__ __forceinline__ bf16_t f2bf(float f) { return (bf16_t)f; }  // RNE fptrunc

__device__ __forceinline__ bf16x8 cvt8(const float4 lo, const float4 hi) {
    bf16x8 r;
    r[0] = (bf16_t)lo.x; r[1] = (bf16_t)lo.y; r[2] = (bf16_t)lo.z; r[3] = (bf16_t)lo.w;
    r[4] = (bf16_t)hi.x; r[5] = (bf16_t)hi.y; r[6] = (bf16_t)hi.z; r[7] = (bf16_t)hi.w;
    return r;
}

// ---------------------------------------------------------------------------
// Kernel 1 (round-3 version, measured ~167 us, WRITE_SIZE 48 MB):
// qkv = X @ W^T + b (fp32 in, bf16 MFMA, fp32 acc), fused RoPE on q,k;
// scatter bf16 to [b][h][s][d] workspace for q, k AND v (contiguous along
// dim across lanes -> stores merge; the [d][s] v-scatter caused 3 GB of
// write amplification in round 4 and is banned).
// ---------------------------------------------------------------------------
__global__ __launch_bounds__(256, 3)
void qkv_rope_kernel(const float* __restrict__ X, const float* __restrict__ W,
                     const float* __restrict__ bias,
                     bf16_t* __restrict__ qws, bf16_t* __restrict__ kws,
                     bf16_t* __restrict__ vws)
{
    __shared__ bf16_t As[128 * 32];   // 8 KB, [row][32] bf16 (16-dword rows)
    __shared__ bf16_t Bs[128 * 32];   // 8 KB

    const int tid  = threadIdx.x;
    const int wave = tid >> 6;
    const int lane = tid & 63;
    const int l15  = lane & 15;
    const int quad = lane >> 4;
    const int wm   = wave >> 1;
    const int wn   = wave & 1;
    const int m0   = blockIdx.y * 128;
    const int n0   = blockIdx.x * 128;

    const int b0   = tid;
    const int b1   = tid + 256;
    const int r0   = b0 >> 2, c0 = (b0 & 3) * 8;
    const int r1   = b1 >> 2, c1 = (b1 & 3) * 8;

    const float* gA0 = X + (size_t)(m0 + r0) * HD + c0;
    const float* gA1 = X + (size_t)(m0 + r1) * HD + c1;
    const float* gB0 = W + (size_t)(n0 + r0) * HD + c0;
    const float* gB1 = W + (size_t)(n0 + r1) * HD + c1;

    floatx4 acc[4][4];
#pragma unroll
    for (int i = 0; i < 4; ++i)
#pragma unroll
        for (int j = 0; j < 4; ++j)
            acc[i][j] = (floatx4){0.f, 0.f, 0.f, 0.f};

    float4 a0l = *(const float4*)(gA0);     float4 a0h = *(const float4*)(gA0 + 4);
    float4 a1l = *(const float4*)(gA1);     float4 a1h = *(const float4*)(gA1 + 4);
    float4 w0l = *(const float4*)(gB0);     float4 w0h = *(const float4*)(gB0 + 4);
    float4 w1l = *(const float4*)(gB1);     float4 w1h = *(const float4*)(gB1 + 4);

    for (int kt = 0; kt < 32; ++kt) {
        *(bf16x8*)(As + r0 * 32 + c0) = cvt8(a0l, a0h);
        *(bf16x8*)(As + r1 * 32 + c1) = cvt8(a1l, a1h);
        *(bf16x8*)(Bs + r0 * 32 + c0) = cvt8(w0l, w0h);
        *(bf16x8*)(Bs + r1 * 32 + c1) = cvt8(w1l, w1h);
        __syncthreads();

        if (kt + 1 < 32) {
            const int k0 = (kt + 1) * 32;
            a0l = *(const float4*)(gA0 + k0);  a0h = *(const float4*)(gA0 + k0 + 4);
            a1l = *(const float4*)(gA1 + k0);  a1h = *(const float4*)(gA1 + k0 + 4);
            w0l = *(const float4*)(gB0 + k0);  w0h = *(const float4*)(gB0 + k0 + 4);
            w1l = *(const float4*)(gB1 + k0);  w1h = *(const float4*)(gB1 + k0 + 4);
        }

        bf16x8 af[4], bfr[4];
#pragma unroll
        for (int t = 0; t < 4; ++t) {
            af[t]  = *(const bf16x8*)(As + (wm * 64 + t * 16 + l15) * 32 + quad * 8);
            bfr[t] = *(const bf16x8*)(Bs + (wn * 64 + t * 16 + l15) * 32 + quad * 8);
        }
#pragma unroll
        for (int i = 0; i < 4; ++i)
#pragma unroll
            for (int j = 0; j < 4; ++j)
                acc[i][j] = __builtin_amdgcn_mfma_f32_16x16x32_bf16(
                    af[i], bfr[j], acc[i][j], 0, 0, 0);
        __syncthreads();
    }

    // Epilogue: bias + RoPE + scatter. C/D: col=lane&15, row=quad*4+reg.
#pragma unroll
    for (int i = 0; i < 4; ++i) {
        const int mrow_base = m0 + wm * 64 + i * 16 + quad * 4;
#pragma unroll
        for (int j = 0; j < 2; ++j) {
            const int n1 = n0 + wn * 64 + j * 16 + l15;    // dim in [0,32)
            const int n2 = n1 + 32;
            const float b1 = bias[n1];
            const float b2 = bias[n2];
            const int which = n1 >> 10;          // 0=q 1=k 2=v
            const int hd    = n1 & 1023;
            const int head  = hd >> 6;
            const int dim   = hd & 63;           // < 32 by construction
            const float inv_freq = expf(-(float)dim * 0.28782313662425572f);
            bf16_t* outp = (which == 0) ? qws : (which == 1) ? kws : vws;
#pragma unroll
            for (int r = 0; r < 4; ++r) {
                const int mrow = mrow_base + r;
                const int s    = mrow & (S_LEN - 1);
                const int bb   = mrow >> 11;
                float x1 = acc[i][j][r]     + b1;
                float x2 = acc[i][j + 2][r] + b2;
                float o1, o2;
                if (which < 2) {
                    const float ang = (float)s * inv_freq;
                    const float cs = cosf(ang);
                    const float sn = sinf(ang);
                    o1 = x1 * cs - x2 * sn;
                    o2 = x2 * cs + x1 * sn;
                } else {
                    o1 = x1; o2 = x2;
                }
                const size_t off = ((size_t)(bb * NHEAD + head) * S_LEN + s) * DHEAD + dim;
                outp[off]      = f2bf(o1);
                outp[off + 32] = f2bf(o2);
            }
        }
    }
}

// ---------------------------------------------------------------------------
// Kernel 2: flash attention. Block = (bh, 128 q-rows); 4 waves x 32 q-rows.
// Q fragments persist in registers. K [t][d] staged coalesced (stride 72).
// V staged coalesced then transposed into Vt [d][t] with stride 70 elems
// (35 dwords == 3 mod 32): per-instruction banks = {0,8,16,24}+srow/2 -> all
// 32 banks exactly once, conflict-free writes; reads 4x b32, <=2-way (free).
// P round-trips a wave-private stride-76 slab (conflict-free writes).
// ---------------------------------------------------------------------------
#define STK 72
#define STV 70
#define STP 76

__device__ __forceinline__ bf16x8 ldsT8(const bf16_t* p) {
    // 4-byte-aligned gather of 8 consecutive bf16 (element offset is even)
    uint4 u;
    u.x = *(const unsigned*)(p);
    u.y = *(const unsigned*)(p + 2);
    u.z = *(const unsigned*)(p + 4);
    u.w = *(const unsigned*)(p + 6);
    return __builtin_bit_cast(bf16x8, u);
}

__global__ __launch_bounds__(256, 3)
void attn_kernel(const bf16_t* __restrict__ qws, const bf16_t* __restrict__ kws,
                 const bf16_t* __restrict__ vws, float* __restrict__ out)
{
    __shared__ bf16_t Ks[64 * STK];    // 9216 B
    __shared__ bf16_t Vt[64 * STV];    // 8960 B  (V^T: [d][t], stride 70)
    __shared__ bf16_t Ps[128 * STP];   // 19456 B (wave-private 32-row slabs)

    const int tid  = threadIdx.x;
    const int wave = tid >> 6;
    const int lane = tid & 63;
    const int l15  = lane & 15;
    const int quad = lane >> 4;
    const int qt   = blockIdx.x;          // 0..15 (128 q-rows each)
    const int bh   = blockIdx.y;          // 0..63
    const size_t baseS = (size_t)bh * S_LEN * DHEAD;   // q,k,v: [s][d]
    const int q0 = qt * 128 + wave * 32;

    // Q fragments: persist across the whole loop. A[m=q][k=d].
    bf16x8 aq[2][2];
#pragma unroll
    for (int qsub = 0; qsub < 2; ++qsub)
#pragma unroll
        for (int kb = 0; kb < 2; ++kb)
            aq[qsub][kb] = *(const bf16x8*)(qws + baseS +
                (size_t)(q0 + qsub * 16 + l15) * DHEAD + kb * 32 + quad * 8);

    // staging coords: 64 rows x 64 cols, 2 x uint4 per thread per matrix
    const int srow = tid >> 2;
    const int scol = (tid & 3) * 8;

    uint4 kreg[2], vreg[2];
#pragma unroll
    for (int jj = 0; jj < 2; ++jj) {
        kreg[jj] = *(const uint4*)(kws + baseS + (size_t)srow * DHEAD + scol + jj * 32);
        vreg[jj] = *(const uint4*)(vws + baseS + (size_t)srow * DHEAD + scol + jj * 32);
    }

    float m_i[2][4], l_i[2][4], alpha[2][4];
    floatx4 o_acc[2][4];
#pragma unroll
    for (int qsub = 0; qsub < 2; ++qsub) {
#pragma unroll
        for (int r = 0; r < 4; ++r) { m_i[qsub][r] = -1e30f; l_i[qsub][r] = 0.0f; }
#pragma unroll
        for (int dt = 0; dt < 4; ++dt) o_acc[qsub][dt] = (floatx4){0.f, 0.f, 0.f, 0.f};
    }

    for (int kt = 0; kt < 32; ++kt) {
        // write prefetched tile to LDS: K row-major, V transposed
#pragma unroll
        for (int jj = 0; jj < 2; ++jj) {
            *(uint4*)(Ks + srow * STK + scol + jj * 32) = kreg[jj];
            bf16_t vv[8];
            *(uint4*)vv = vreg[jj];
#pragma unroll
            for (int e = 0; e < 8; ++e)
                Vt[(scol + jj * 32 + e) * STV + srow] = vv[e];
        }
        __syncthreads();

        // prefetch next tile
        if (kt + 1 < 32) {
            const int t0 = (kt + 1) * 64;
#pragma unroll
            for (int jj = 0; jj < 2; ++jj) {
                kreg[jj] = *(const uint4*)(kws + baseS + (size_t)(t0 + srow) * DHEAD + scol + jj * 32);
                vreg[jj] = *(const uint4*)(vws + baseS + (size_t)(t0 + srow) * DHEAD + scol + jj * 32);
            }
        }

        // K fragments: B[n=t][k=d]
        bf16x8 bk[2][4];
#pragma unroll
        for (int kb = 0; kb < 2; ++kb)
#pragma unroll
            for (int nt = 0; nt < 4; ++nt)
                bk[kb][nt] = *(const bf16x8*)(Ks + (nt * 16 + l15) * STK + kb * 32 + quad * 8);

        // scores
        floatx4 sc[2][4];
#pragma unroll
        for (int qsub = 0; qsub < 2; ++qsub)
#pragma unroll
            for (int nt = 0; nt < 4; ++nt) {
                floatx4 s4 = (floatx4){0.f, 0.f, 0.f, 0.f};
#pragma unroll
                for (int kb = 0; kb < 2; ++kb)
                    s4 = __builtin_amdgcn_mfma_f32_16x16x32_bf16(
                        aq[qsub][kb], bk[kb][nt], s4, 0, 0, 0);
                sc[qsub][nt] = s4 * 0.125f;
            }

        // online softmax + P store (wave-private Ps slab, no barrier needed)
#pragma unroll
        for (int qsub = 0; qsub < 2; ++qsub) {
            float mnew[4], rsum[4];
#pragma unroll
            for (int r = 0; r < 4; ++r) {
                float mx = fmaxf(fmaxf(sc[qsub][0][r], sc[qsub][1][r]),
                                 fmaxf(sc[qsub][2][r], sc[qsub][3][r]));
#pragma unroll
                for (int off = 1; off < 16; off <<= 1)
                    mx = fmaxf(mx, __shfl_xor(mx, off, 64));
                mnew[r]        = fmaxf(m_i[qsub][r], mx);
                alpha[qsub][r] = __expf(m_i[qsub][r] - mnew[r]);
                rsum[r]        = 0.0f;
            }
#pragma unroll
            for (int nt = 0; nt < 4; ++nt)
#pragma unroll
                for (int r = 0; r < 4; ++r) {
                    const float p = __expf(sc[qsub][nt][r] - mnew[r]);
                    const bf16_t pb = f2bf(p);
                    rsum[r] += bf2f(pb);
                    Ps[(wave * 32 + qsub * 16 + quad * 4 + r) * STP + nt * 16 + l15] = pb;
                }
#pragma unroll
            for (int r = 0; r < 4; ++r) {
                float sm = rsum[r];
#pragma unroll
                for (int off = 1; off < 16; off <<= 1)
                    sm += __shfl_xor(sm, off, 64);
                l_i[qsub][r] = l_i[qsub][r] * alpha[qsub][r] + sm;
                m_i[qsub][r] = mnew[r];
            }
        }

        // rescale O
#pragma unroll
        for (int qsub = 0; qsub < 2; ++qsub)
#pragma unroll
            for (int dt = 0; dt < 4; ++dt)
#pragma unroll
                for (int r = 0; r < 4; ++r)
                    o_acc[qsub][dt][r] *= alpha[qsub][r];

        // O += P V : A = P (LDS), B = V^T (Vt, [d][t])
#pragma unroll
        for (int kb = 0; kb < 2; ++kb) {
            bf16x8 bv[4];
#pragma unroll
            for (int dt = 0; dt < 4; ++dt)
                bv[dt] = ldsT8(Vt + (dt * 16 + l15) * STV + kb * 32 + quad * 8);
#pragma unroll
            for (int qsub = 0; qsub < 2; ++qsub) {
                const int pbase = (wave * 32 + qsub * 16 + l15) * STP + kb * 32 + quad * 8;
                bf16x4 plo = *(const bf16x4*)(Ps + pbase);
                bf16x4 phi = *(const bf16x4*)(Ps + pbase + 4);
                bf16x8 ap = __builtin_shufflevector(plo, phi, 0, 1, 2, 3, 4, 5, 6, 7);
#pragma unroll
                for (int dt = 0; dt < 4; ++dt)
                    o_acc[qsub][dt] = __builtin_amdgcn_mfma_f32_16x16x32_bf16(
                        ap, bv[dt], o_acc[qsub][dt], 0, 0, 0);
            }
        }
        __syncthreads();
    }

    // normalize + store out[b][s][h*64+d] (fp32)
    const int bb = bh >> 4, hh = bh & 15;
#pragma unroll
    for (int qsub = 0; qsub < 2; ++qsub)
#pragma unroll
        for (int r = 0; r < 4; ++r) {
            const float inv = 1.0f / l_i[qsub][r];
            const int s = q0 + qsub * 16 + quad * 4 + r;
            const size_t off0 = ((size_t)(bb * S_LEN + s)) * HD + hh * DHEAD;
#pragma unroll
            for (int dt = 0; dt < 4; ++dt)
                out[off0 + dt * 16 + l15] = o_acc[qsub][dt][r] * inv;
        }
}

extern "C" void kernel_launch(void* const* d_in, const int* in_sizes, int n_in,
                              void* d_out, int out_size, void* d_ws, size_t ws_size,
                              hipStream_t stream) {
    const float* X    = (const float*)d_in[0];   // (4,2048,1024) fp32
    const float* W    = (const float*)d_in[1];   // (3072,1024) fp32
    const float* bias = (const float*)d_in[2];   // (3072,) fp32
    float* out = (float*)d_out;                  // (4,2048,1024) fp32

    const size_t per = (size_t)B_SZ * NHEAD * S_LEN * DHEAD;   // 8.39M elems
    bf16_t* qws = (bf16_t*)d_ws;
    bf16_t* kws = qws + per;
    bf16_t* vws = kws + per;

    qkv_rope_kernel<<<dim3(N3 / 128, M_ROWS / 128), 256, 0, stream>>>(
        X, W, bias, qws, kws, vws);
    attn_kernel<<<dim3(S_LEN / 128, B_SZ * NHEAD), 256, 0, stream>>>(
        qws, kws, vws, out);
}